// Round 11
// baseline (1767.288 us; speedup 1.0000x reference)
//
#include <hip/hip_runtime.h>
#include <cstdint>

// PointNetSetAbstraction: B=16,N=4096,C=64 -> FPS(1024) -> kNN(32) -> MLP 67->64->64->128 (BN+ReLU) -> maxpool
#define NB   16
#define NPT  4096
#define CINP 64
#define SP   1024
#define KNB  32
#define NROWS (NB*SP*KNB)      // 524288
#define NT_F  524288.0f
#define NBLK12 4096            // layer1/2: 128 rows/block
#define NBLK3  8192            // layer3:   64 rows/block

typedef float v2f __attribute__((ext_vector_type(2)));

// exact (non-contracted) squared distance, matches XLA mul+add order ((dx^2+dy^2)+dz^2)
__device__ __forceinline__ float sqdist3(float ax, float ay, float az,
                                         float bx, float by, float bz) {
  float dx = ax - bx, dy = ay - by, dz = az - bz;
  return __fadd_rn(__fadd_rn(__fmul_rn(dx, dx), __fmul_rn(dy, dy)), __fmul_rn(dz, dz));
}

// ---- DPP wave64 reductions (VALU-only; result broadcast via readlane 63) ----
#define DPP_STAGE_MAXF(v, ctrl)                                                   \
  do {                                                                            \
    int _t = __builtin_amdgcn_update_dpp(0, __float_as_int(v), ctrl, 0xf, 0xf, false); \
    v = fmaxf(v, __int_as_float(_t));                                             \
  } while (0)

__device__ __forceinline__ float wave_max_f32(float v) {  // v must be >= 0
  DPP_STAGE_MAXF(v, 0x111);  // row_shr:1
  DPP_STAGE_MAXF(v, 0x112);  // row_shr:2
  DPP_STAGE_MAXF(v, 0x114);  // row_shr:4
  DPP_STAGE_MAXF(v, 0x118);  // row_shr:8
  DPP_STAGE_MAXF(v, 0x142);  // row_bcast:15
  DPP_STAGE_MAXF(v, 0x143);  // row_bcast:31
  return __int_as_float(__builtin_amdgcn_readlane(__float_as_int(v), 63));
}

#define DPP_STAGE_ADDI(v, ctrl)                                                   \
  do {                                                                            \
    int _t = __builtin_amdgcn_update_dpp(0, (v), ctrl, 0xf, 0xf, false);          \
    v += _t;                                                                      \
  } while (0)

__device__ __forceinline__ int wave_sum_i32(int v) {
  DPP_STAGE_ADDI(v, 0x111);
  DPP_STAGE_ADDI(v, 0x112);
  DPP_STAGE_ADDI(v, 0x114);
  DPP_STAGE_ADDI(v, 0x118);
  DPP_STAGE_ADDI(v, 0x142);
  DPP_STAGE_ADDI(v, 0x143);
  return __builtin_amdgcn_readlane(v, 63);
}

// ---------------------------------------------------------------- FPS
// One block per batch. 256 threads x 16 CONTIGUOUS points each (thread t owns
// [16t,16t+16) so tie-index is lane-monotonic -> ballot+ffs replaces a 6-stage
// DPP min). Serial 1024 steps with NO barrier: waves exchange per-step
// {dist,idx,tag} via a volatile LDS message-passing protocol (data written
// before tag; same-wave ds ops retire in order; double-buffer bounds skew to
// 1 step so slots are never overwritten while readable). Tie rule: lowest
// index (jnp.argmax). Distances: exact (contract-off) (dx^2+dy^2)+dz^2.
__global__ __launch_bounds__(256) void fps_kernel(const float* __restrict__ xyz,
                                                  float* __restrict__ newxyz) {
#pragma clang fp contract(off)
  const int b = blockIdx.x, t = threadIdx.x;
  __shared__ __align__(16) float s4[NPT * 4];  // xyz padded to 4
  __shared__ unsigned s_tag[2][4], s_hi[2][4], s_lo[2][4];
  volatile unsigned* vtag = &s_tag[0][0];
  volatile unsigned* vhi  = &s_hi[0][0];
  volatile unsigned* vlo  = &s_lo[0][0];
  const float* gx = xyz + b * NPT * 3;
  for (int i = t; i < NPT * 3; i += 256) s4[(i / 3) * 4 + (i % 3)] = gx[i];
  if (t < 8) s_tag[t >> 2][t & 3] = 0xFFFFFFFFu;  // invalid tag (never == it)
  __syncthreads();
  v2f px[8], py[8], pz[8], dst[8];
#pragma unroll
  for (int k = 0; k < 8; ++k) {  // contiguous: points 16t+2k, 16t+2k+1
    float4 a = *(const float4*)&s4[(t * 16 + 2 * k) * 4];
    float4 c = *(const float4*)&s4[(t * 16 + 2 * k + 1) * 4];
    px[k].x = a.x; px[k].y = c.x;
    py[k].x = a.y; py[k].y = c.y;
    pz[k].x = a.z; pz[k].y = c.z;
    dst[k].x = 1e10f; dst[k].y = 1e10f;
  }
  float cx = s4[0], cy = s4[1], cz = s4[2];  // start = index 0
  const int w = t >> 6;
  int buf = 0;
  for (int it = 0; it < SP; ++it) {
    if (t == 0) {
      float* o = newxyz + (b * SP + it) * 3;
      o[0] = cx; o[1] = cy; o[2] = cz;
    }
    v2f vcx; vcx.x = cx; vcx.y = cx;
    v2f vcy; vcy.x = cy; vcy.y = cy;
    v2f vcz; vcz.x = cz; vcz.y = cz;
    float bd = -1.0f; int bi = 0;
#pragma unroll
    for (int k = 0; k < 8; ++k) {
      v2f dx = px[k] - vcx;
      v2f dy = py[k] - vcy;
      v2f dz = pz[k] - vcz;
      v2f dd = (dx * dx + dy * dy) + dz * dz;  // per-component, no fma
      float n0 = fminf(dst[k].x, dd.x);
      float n1 = fminf(dst[k].y, dd.y);
      dst[k].x = n0; dst[k].y = n1;
      if (n0 > bd) { bd = n0; bi = t * 16 + 2 * k; }      // ascending idx scan:
      if (n1 > bd) { bd = n1; bi = t * 16 + 2 * k + 1; }  // strict > keeps lowest
    }
    float dw = wave_max_f32(bd);
    unsigned long long mask = __ballot(bd == dw);
    int wl = __ffsll(mask) - 1;                       // lowest candidate lane
    unsigned iw = (unsigned)__builtin_amdgcn_readlane(bi, wl);  // its index (lane-monotonic)
    if ((t & 63) == 0) {  // volatile writes: data first, tag last (in-order ds FIFO)
      vhi[buf * 4 + w] = __float_as_uint(dw);
      vlo[buf * 4 + w] = 4095u - iw;
      vtag[buf * 4 + w] = (unsigned)it;
    }
    for (;;) {  // spin until all 4 waves posted this step
      unsigned t0 = vtag[buf * 4 + 0], t1 = vtag[buf * 4 + 1];
      unsigned t2 = vtag[buf * 4 + 2], t3 = vtag[buf * 4 + 3];
      if (t0 == (unsigned)it && t1 == (unsigned)it &&
          t2 == (unsigned)it && t3 == (unsigned)it) break;
    }
    unsigned long long k0 = ((unsigned long long)vhi[buf * 4 + 0] << 32) | vlo[buf * 4 + 0];
    unsigned long long k1 = ((unsigned long long)vhi[buf * 4 + 1] << 32) | vlo[buf * 4 + 1];
    unsigned long long k2 = ((unsigned long long)vhi[buf * 4 + 2] << 32) | vlo[buf * 4 + 2];
    unsigned long long k3 = ((unsigned long long)vhi[buf * 4 + 3] << 32) | vlo[buf * 4 + 3];
    unsigned long long ka = k0 > k1 ? k0 : k1;
    unsigned long long kb = k2 > k3 ? k2 : k3;
    unsigned long long km = ka > kb ? ka : kb;
    int p = 4095 - (int)(km & 0xFFFull);
    float4 cc = *(const float4*)&s4[p * 4];
    cx = cc.x; cy = cc.y; cz = cc.z;
    buf ^= 1;
  }
}

// ---------------------------------------------------------------- kNN
// One wave per query (4 waves/block). 64 distances/lane in registers.
// Radix binary search on float bits for the exact 32nd-smallest value
// (DPP sum for the wave count), then collect (<T) plus index-ordered (==T)
// fills. Order within the 32 is irrelevant downstream (permutation-invariant).
__global__ __launch_bounds__(256) void knn_kernel(const float* __restrict__ xyz,
                                                  const float* __restrict__ newxyz,
                                                  int* __restrict__ gidx) {
  const int t = threadIdx.x, lane = t & 63, w = t >> 6;
  const int q = blockIdx.x * 4 + w;  // 0..16383
  const int b = q >> 10;
  const float* nx = newxyz + q * 3;
  const float qx = nx[0], qy = nx[1], qz = nx[2];
  const float* xb = xyz + b * NPT * 3;
  float d[64];
#pragma unroll
  for (int j = 0; j < 64; ++j) {
    int p = j * 64 + lane;
    d[j] = sqdist3(xb[p * 3], xb[p * 3 + 1], xb[p * 3 + 2], qx, qy, qz);
  }
  unsigned V = 0;  // becomes bit pattern of the 32nd smallest distance
  for (int bit = 30; bit >= 0; --bit) {
    unsigned cand = V | (1u << bit);
    int c = 0;
#pragma unroll
    for (int j = 0; j < 64; ++j) c += (__float_as_uint(d[j]) < cand) ? 1 : 0;
    int ct = wave_sum_i32(c);
    if (ct < KNB) V = cand;
  }
  __shared__ int s_cnt[4], s_eqcnt[4], s_eq[4][64];
  if (lane == 0) { s_cnt[w] = 0; s_eqcnt[w] = 0; }
  __syncthreads();
  int* gout = gidx + q * KNB;
#pragma unroll
  for (int j = 0; j < 64; ++j) {
    unsigned db = __float_as_uint(d[j]);
    if (db < V) {
      int pos = atomicAdd(&s_cnt[w], 1);
      if (pos < KNB) gout[pos] = j * 64 + lane;
    } else if (db == V) {
      int pos = atomicAdd(&s_eqcnt[w], 1);
      if (pos < 64) s_eq[w][pos] = j * 64 + lane;
    }
  }
  __syncthreads();
  if (lane == 0) {  // fill remaining slots with smallest-index ties
    int c1 = s_cnt[w]; if (c1 > KNB) c1 = KNB;
    int ne = s_eqcnt[w]; if (ne > 64) ne = 64;
    int need = KNB - c1;
    for (int m = 0; m < need; ++m) {
      int bi = -1, bv = 0x7fffffff;
      for (int e = 0; e < ne; ++e) {
        int v = s_eq[w][e];
        if (v < bv) { bv = v; bi = e; }
      }
      gout[c1 + m] = bv;
      if (bi >= 0) s_eq[w][bi] = 0x7fffffff;
    }
  }
}

// ---------------------------------------------------------------- layer 1 (gather + 67->64 + stats)
// 128 rows x 64 outs per block; 4 rows x 8 outs per thread (32 fma / 3 b128).
// Stats partials written COALESCED as part[blk][2][64].
__global__ __launch_bounds__(256) void layer1_kernel(
    const float* __restrict__ xyz, const float* __restrict__ points,
    const float* __restrict__ newxyz, const int* __restrict__ gidx,
    const float* __restrict__ w1, const float* __restrict__ b1,
    float* __restrict__ h1, float* __restrict__ part) {
  const int t = threadIdx.x, blk = blockIdx.x;
  const int R0 = blk * 128;
  const int b = R0 >> 15;
  __shared__ __align__(16) float xs[67][132];
  __shared__ __align__(16) float wsm[67][68];
  __shared__ float red[2][32][65];
  {
    int o = t & 63;
    for (int c = t >> 6; c < 67; c += 4) wsm[c][o] = w1[o * 67 + c];
  }
  {
    int r = t >> 1, q = t & 1;
    int R = R0 + r;
    int idx = gidx[R];
    if (q == 0) {
      const float* xp = xyz + (size_t)(b * NPT + idx) * 3;
      const float* nq = newxyz + (size_t)(R >> 5) * 3;  // R>>5 == b*1024+s
      xs[0][r] = xp[0] - nq[0];
      xs[1][r] = xp[1] - nq[1];
      xs[2][r] = xp[2] - nq[2];
    }
    const float* pp = points + (size_t)(b * NPT + idx) * CINP + q * 32;
#pragma unroll
    for (int i = 0; i < 8; ++i) {
      float4 v = *(const float4*)(pp + i * 4);
      int c = 3 + q * 32 + i * 4;
      xs[c][r] = v.x; xs[c + 1][r] = v.y; xs[c + 2][r] = v.z; xs[c + 3][r] = v.w;
    }
  }
  __syncthreads();
  const int tr = t & 31, to = t >> 5;  // 4 rows x 8 outs
  float acc[4][8];
#pragma unroll
  for (int j = 0; j < 8; ++j) {
    float bb = b1[to * 8 + j];
#pragma unroll
    for (int i = 0; i < 4; ++i) acc[i][j] = bb;
  }
  for (int c = 0; c < 67; ++c) {
    float4 xv = *(const float4*)&xs[c][tr * 4];
    float4 w0 = *(const float4*)&wsm[c][to * 8];
    float4 w1v = *(const float4*)&wsm[c][to * 8 + 4];
    float xa[4] = {xv.x, xv.y, xv.z, xv.w};
    float wa[8] = {w0.x, w0.y, w0.z, w0.w, w1v.x, w1v.y, w1v.z, w1v.w};
#pragma unroll
    for (int i = 0; i < 4; ++i)
#pragma unroll
      for (int j = 0; j < 8; ++j) acc[i][j] += xa[i] * wa[j];
  }
#pragma unroll
  for (int i = 0; i < 4; ++i) {
    float4 s0; s0.x = acc[i][0]; s0.y = acc[i][1]; s0.z = acc[i][2]; s0.w = acc[i][3];
    float4 s1; s1.x = acc[i][4]; s1.y = acc[i][5]; s1.z = acc[i][6]; s1.w = acc[i][7];
    float* hp = &h1[(size_t)(R0 + tr * 4 + i) * 64 + to * 8];
    *(float4*)hp = s0;
    *(float4*)(hp + 4) = s1;
  }
#pragma unroll
  for (int j = 0; j < 8; ++j) {
    float s1 = acc[0][j] + acc[1][j] + acc[2][j] + acc[3][j];
    float s2 = acc[0][j] * acc[0][j] + acc[1][j] * acc[1][j] +
               acc[2][j] * acc[2][j] + acc[3][j] * acc[3][j];
    red[0][tr][to * 8 + j] = s1;
    red[1][tr][to * 8 + j] = s2;
  }
  __syncthreads();
  if (t < 128) {
    int stat = t >> 6, o = t & 63;
    float v = 0.f;
#pragma unroll
    for (int k = 0; k < 32; ++k) v += red[stat][k][o];
    part[(size_t)blk * 128 + t] = v;  // coalesced [blk][2][64]
  }
}

// ---------------------------------------------------------------- layer 2 (bn1+relu fold, 64->64 + stats)
// 128 rows x 64 outs; runs IN-PLACE (hin/hout alias -> NOT restrict; stage to
// LDS first; blocks own disjoint rows). Coalesced stats like layer1.
__global__ __launch_bounds__(256) void layer2_kernel(
    const float* hin, const float* __restrict__ bn,
    const float* __restrict__ w2, const float* __restrict__ b2,
    float* hout, float* __restrict__ part) {
  const int t = threadIdx.x, blk = blockIdx.x;
  const size_t R0 = (size_t)blk * 128;
  __shared__ __align__(16) float xs[64][132];
  __shared__ __align__(16) float wsm[64][68];
  __shared__ float red[2][32][65];
  {
    int o = t & 63;
    for (int c = t >> 6; c < 64; c += 4) wsm[c][o] = w2[o * 64 + c];
  }
  {
    int r = t >> 1, q = t & 1;
    const float* hp = hin + (R0 + r) * 64 + q * 32;
#pragma unroll
    for (int i = 0; i < 8; ++i) {
      int c = q * 32 + i * 4;
      float4 v = *(const float4*)(hp + i * 4);
      float4 sc = *(const float4*)(bn + c);
      float4 sh = *(const float4*)(bn + 64 + c);
      xs[c][r]     = fmaxf(v.x * sc.x + sh.x, 0.f);
      xs[c + 1][r] = fmaxf(v.y * sc.y + sh.y, 0.f);
      xs[c + 2][r] = fmaxf(v.z * sc.z + sh.z, 0.f);
      xs[c + 3][r] = fmaxf(v.w * sc.w + sh.w, 0.f);
    }
  }
  __syncthreads();
  const int tr = t & 31, to = t >> 5;
  float acc[4][8];
#pragma unroll
  for (int j = 0; j < 8; ++j) {
    float bb = b2[to * 8 + j];
#pragma unroll
    for (int i = 0; i < 4; ++i) acc[i][j] = bb;
  }
  for (int c = 0; c < 64; ++c) {
    float4 xv = *(const float4*)&xs[c][tr * 4];
    float4 w0 = *(const float4*)&wsm[c][to * 8];
    float4 w1v = *(const float4*)&wsm[c][to * 8 + 4];
    float xa[4] = {xv.x, xv.y, xv.z, xv.w};
    float wa[8] = {w0.x, w0.y, w0.z, w0.w, w1v.x, w1v.y, w1v.z, w1v.w};
#pragma unroll
    for (int i = 0; i < 4; ++i)
#pragma unroll
      for (int j = 0; j < 8; ++j) acc[i][j] += xa[i] * wa[j];
  }
#pragma unroll
  for (int i = 0; i < 4; ++i) {
    float4 s0; s0.x = acc[i][0]; s0.y = acc[i][1]; s0.z = acc[i][2]; s0.w = acc[i][3];
    float4 s1; s1.x = acc[i][4]; s1.y = acc[i][5]; s1.z = acc[i][6]; s1.w = acc[i][7];
    float* hp = &hout[(R0 + tr * 4 + i) * 64 + to * 8];
    *(float4*)hp = s0;
    *(float4*)(hp + 4) = s1;
  }
#pragma unroll
  for (int j = 0; j < 8; ++j) {
    float s1 = acc[0][j] + acc[1][j] + acc[2][j] + acc[3][j];
    float s2 = acc[0][j] * acc[0][j] + acc[1][j] * acc[1][j] +
               acc[2][j] * acc[2][j] + acc[3][j] * acc[3][j];
    red[0][tr][to * 8 + j] = s1;
    red[1][tr][to * 8 + j] = s2;
  }
  __syncthreads();
  if (t < 128) {
    int stat = t >> 6, o = t & 63;
    float v = 0.f;
#pragma unroll
    for (int k = 0; k < 32; ++k) v += red[stat][k][o];
    part[(size_t)blk * 128 + t] = v;  // coalesced [blk][2][64]
  }
}

// ---------------------------------------------------------------- layer 3 (bn2+relu fold, 64->128, stats + max/min pool over k)
// red overlay stride 129; coalesced stats part[blk][2][128].
__global__ __launch_bounds__(256) void layer3_kernel(
    const float* __restrict__ hin, const float* __restrict__ bn,
    const float* __restrict__ w3, const float* __restrict__ b3,
    float* __restrict__ maxh, float* __restrict__ minh, float* __restrict__ part) {
  const int t = threadIdx.x, blk = blockIdx.x;
  const size_t R0 = (size_t)blk * 64;
  __shared__ __align__(16) float smem[64 * 68 + 64 * 136];  // xs | wsm (red overlays xs later)
  float* xs = smem;            // [64][68]
  float* wsm = smem + 64 * 68; // [64][136]
  {
    int o = t & 127, q = t >> 7;
    for (int c = q; c < 64; c += 2) wsm[c * 136 + o] = w3[o * 64 + c];
  }
  {
    int r = t >> 2, q = t & 3;
    const float* hp = hin + (R0 + r) * 64 + q * 16;
#pragma unroll
    for (int i = 0; i < 4; ++i) {
      int c = q * 16 + i * 4;
      float4 v = *(const float4*)(hp + i * 4);
      float4 sc = *(const float4*)(bn + c);
      float4 sh = *(const float4*)(bn + 64 + c);
      xs[c * 68 + r]       = fmaxf(v.x * sc.x + sh.x, 0.f);
      xs[(c + 1) * 68 + r] = fmaxf(v.y * sc.y + sh.y, 0.f);
      xs[(c + 2) * 68 + r] = fmaxf(v.z * sc.z + sh.z, 0.f);
      xs[(c + 3) * 68 + r] = fmaxf(v.w * sc.w + sh.w, 0.f);
    }
  }
  __syncthreads();
  const int tr = t & 15, to = t >> 4;  // 4 rows x 8 outs per thread
  float acc[4][8];
#pragma unroll
  for (int j = 0; j < 8; ++j) {
    float bb = b3[to * 8 + j];
#pragma unroll
    for (int i = 0; i < 4; ++i) acc[i][j] = bb;
  }
  for (int c = 0; c < 64; ++c) {
    float4 xv = *(const float4*)&xs[c * 68 + tr * 4];
    float4 wv0 = *(const float4*)&wsm[c * 136 + to * 8];
    float4 wv1 = *(const float4*)&wsm[c * 136 + to * 8 + 4];
    float xa[4] = {xv.x, xv.y, xv.z, xv.w};
    float wa[8] = {wv0.x, wv0.y, wv0.z, wv0.w, wv1.x, wv1.y, wv1.z, wv1.w};
#pragma unroll
    for (int i = 0; i < 4; ++i)
#pragma unroll
      for (int j = 0; j < 8; ++j) acc[i][j] += xa[i] * wa[j];
  }
  __syncthreads();  // xs reads done; reuse as reduction buffer
  float* red = smem;  // [2][16][129] = 4128 floats <= 4352
#pragma unroll
  for (int j = 0; j < 8; ++j) {
    float s1 = acc[0][j] + acc[1][j] + acc[2][j] + acc[3][j];
    float s2 = acc[0][j] * acc[0][j] + acc[1][j] * acc[1][j] +
               acc[2][j] * acc[2][j] + acc[3][j] * acc[3][j];
    red[(0 * 16 + tr) * 129 + to * 8 + j] = s1;
    red[(1 * 16 + tr) * 129 + to * 8 + j] = s2;
  }
  __syncthreads();
  {
    int stat = t >> 7, o = t & 127;
    float v = 0.f;
#pragma unroll
    for (int k = 0; k < 16; ++k) v += red[(stat * 16 + k) * 129 + o];
    part[(size_t)blk * 256 + t] = v;  // coalesced [blk][2][128]
  }
  __syncthreads();
#pragma unroll
  for (int j = 0; j < 8; ++j) {
    float mx = fmaxf(fmaxf(acc[0][j], acc[1][j]), fmaxf(acc[2][j], acc[3][j]));
    float mn = fminf(fminf(acc[0][j], acc[1][j]), fminf(acc[2][j], acc[3][j]));
    red[(0 * 16 + tr) * 129 + to * 8 + j] = mx;
    red[(1 * 16 + tr) * 129 + to * 8 + j] = mn;
  }
  __syncthreads();
  {
    int g = t >> 7, o = t & 127;  // 2 s-rows per block (k=32 inner)
    float mx = -1e30f, mn = 1e30f;
#pragma unroll
    for (int k = 0; k < 8; ++k) {
      mx = fmaxf(mx, red[(0 * 16 + g * 8 + k) * 129 + o]);
      mn = fminf(mn, red[(1 * 16 + g * 8 + k) * 129 + o]);
    }
    size_t bs = (size_t)blk * 2 + g;
    maxh[bs * 128 + o] = mx;
    minh[bs * 128 + o] = mn;
  }
}

// ---------------------------------------------------------------- BN reduce: part[nblk][2][Cout] column-sum -> scale/shift (1 dispatch/layer)
// One block per channel o; strided reads are L2-resident (part is 2-8 MB).
__global__ __launch_bounds__(256) void bn_reduce(const float* __restrict__ part,
                                                 const float* __restrict__ g,
                                                 const float* __restrict__ be,
                                                 float* __restrict__ bnout,
                                                 int Cout, int nblk) {
  const int o = blockIdx.x, t = threadIdx.x;
  const int row = 2 * Cout;
  float s1 = 0.f, s2 = 0.f;
  for (int r = t; r < nblk; r += 256) {
    const float* p = part + (size_t)r * row;
    s1 += p[o];
    s2 += p[Cout + o];
  }
#pragma unroll
  for (int off = 32; off >= 1; off >>= 1) {
    s1 += __shfl_xor(s1, off);
    s2 += __shfl_xor(s2, off);
  }
  __shared__ float r1[4], r2[4];
  if ((t & 63) == 0) { r1[t >> 6] = s1; r2[t >> 6] = s2; }
  __syncthreads();
  if (t == 0) {
    float S1 = r1[0] + r1[1] + r1[2] + r1[3];
    float S2 = r2[0] + r2[1] + r2[2] + r2[3];
    float m = S1 / NT_F;
    float v = S2 / NT_F - m * m;
    if (v < 0.f) v = 0.f;
    float inv = 1.0f / sqrtf(v + 1e-5f);
    float sc = g[o] * inv;
    bnout[o] = sc;
    bnout[Cout + o] = be[o] - m * sc;
  }
}

// ---------------------------------------------------------------- final: out = max(relu(sc*maxh+sh), relu(sc*minh+sh))
// (exact for max_k relu(sc*h+sh) for any sign of sc)
__global__ __launch_bounds__(256) void finalize_kernel(const float* __restrict__ maxh,
                                                       const float* __restrict__ minh,
                                                       const float* __restrict__ bn,
                                                       float* __restrict__ out2) {
  int i = blockIdx.x * 256 + threadIdx.x;  // 2,097,152 total
  int o = i & 127;
  float sc = bn[o], sh = bn[128 + o];
  float a = sc * maxh[i] + sh;
  float c = sc * minh[i] + sh;
  out2[i] = fmaxf(fmaxf(a, c), 0.f);
}

extern "C" void kernel_launch(void* const* d_in, const int* in_sizes, int n_in,
                              void* d_out, int out_size, void* d_ws, size_t ws_size,
                              hipStream_t stream) {
  const float* xyz = (const float*)d_in[0];
  const float* points = (const float*)d_in[1];
  const float* w1 = (const float*)d_in[2];
  const float* b1 = (const float*)d_in[3];
  const float* g1 = (const float*)d_in[4];
  const float* be1 = (const float*)d_in[5];
  const float* w2 = (const float*)d_in[6];
  const float* b2 = (const float*)d_in[7];
  const float* g2 = (const float*)d_in[8];
  const float* be2 = (const float*)d_in[9];
  const float* w3 = (const float*)d_in[10];
  const float* b3 = (const float*)d_in[11];
  const float* g3 = (const float*)d_in[12];
  const float* be3 = (const float*)d_in[13];

  float* out = (float*)d_out;
  float* newxyz = out;           // [16,1024,3]
  float* out2 = out + 49152;     // [16,1024,128]

  // workspace layout (~154 MiB):
  // [gidx 2MiB (bn buffers @1MiB, used only after layer1 when gidx slot free)]
  // [h 128MiB (layer2 in-place)][part 8MiB][maxh 8MiB][minh 8MiB]
  const size_t MiB = 1u << 20;
  char* wsb = (char*)d_ws;
  int*   gidx = (int*)wsb;
  float* bn1  = (float*)(wsb + 1 * MiB);
  float* bn2  = bn1 + 256;
  float* bn3  = bn2 + 256;
  float* h    = (float*)(wsb + 2 * MiB);
  float* part = (float*)(wsb + 130 * MiB);
  float* maxh = (float*)(wsb + 138 * MiB);
  float* minh = (float*)(wsb + 146 * MiB);

  hipLaunchKernelGGL(fps_kernel, dim3(NB), dim3(256), 0, stream, xyz, newxyz);
  hipLaunchKernelGGL(knn_kernel, dim3(16384 / 4), dim3(256), 0, stream, xyz, newxyz, gidx);
  hipLaunchKernelGGL(layer1_kernel, dim3(NBLK12), dim3(256), 0, stream,
                     xyz, points, newxyz, gidx, w1, b1, h, part);
  hipLaunchKernelGGL(bn_reduce, dim3(64), dim3(256), 0, stream, part, g1, be1, bn1, 64, NBLK12);
  hipLaunchKernelGGL(layer2_kernel, dim3(NBLK12), dim3(256), 0, stream, h, bn1, w2, b2, h, part);
  hipLaunchKernelGGL(bn_reduce, dim3(64), dim3(256), 0, stream, part, g2, be2, bn2, 64, NBLK12);
  hipLaunchKernelGGL(layer3_kernel, dim3(NBLK3), dim3(256), 0, stream,
                     h, bn2, w3, b3, maxh, minh, part);
  hipLaunchKernelGGL(bn_reduce, dim3(128), dim3(256), 0, stream, part, g3, be3, bn3, 128, NBLK3);
  hipLaunchKernelGGL(finalize_kernel, dim3(2097152 / 256), dim3(256), 0, stream,
                     maxh, minh, bn3, out2);
}

// Round 12
// 1333.788 us; speedup vs baseline: 1.3250x; 1.3250x over previous
//
#include <hip/hip_runtime.h>
#include <cstdint>

// PointNetSetAbstraction: B=16,N=4096,C=64 -> FPS(1024) -> kNN(32) -> MLP 67->64->64->128 (BN+ReLU) -> maxpool
#define NB   16
#define NPT  4096
#define CINP 64
#define SP   1024
#define KNB  32
#define NROWS (NB*SP*KNB)      // 524288
#define NT_F  524288.0f
#define NBLK12 4096            // layer1/2: 128 rows/block
#define NBLK3  8192            // layer3:   64 rows/block

typedef float v2f __attribute__((ext_vector_type(2)));

__device__ __forceinline__ v2f splat2(float x) { v2f r; r.x = x; r.y = x; return r; }

// exact (non-contracted) squared distance, matches XLA mul+add order ((dx^2+dy^2)+dz^2)
__device__ __forceinline__ float sqdist3(float ax, float ay, float az,
                                         float bx, float by, float bz) {
  float dx = ax - bx, dy = ay - by, dz = az - bz;
  return __fadd_rn(__fadd_rn(__fmul_rn(dx, dx), __fmul_rn(dy, dy)), __fmul_rn(dz, dz));
}

// ---- DPP wave64 reductions (VALU-only; result broadcast via readlane 63) ----
#define DPP_STAGE_MAXF(v, ctrl)                                                   \
  do {                                                                            \
    int _t = __builtin_amdgcn_update_dpp(0, __float_as_int(v), ctrl, 0xf, 0xf, false); \
    v = fmaxf(v, __int_as_float(_t));                                             \
  } while (0)

__device__ __forceinline__ float wave_max_f32(float v) {  // v must be >= 0
  DPP_STAGE_MAXF(v, 0x111);  // row_shr:1
  DPP_STAGE_MAXF(v, 0x112);  // row_shr:2
  DPP_STAGE_MAXF(v, 0x114);  // row_shr:4
  DPP_STAGE_MAXF(v, 0x118);  // row_shr:8
  DPP_STAGE_MAXF(v, 0x142);  // row_bcast:15
  DPP_STAGE_MAXF(v, 0x143);  // row_bcast:31
  return __int_as_float(__builtin_amdgcn_readlane(__float_as_int(v), 63));
}

#define DPP_STAGE_ADDI(v, ctrl)                                                   \
  do {                                                                            \
    int _t = __builtin_amdgcn_update_dpp(0, (v), ctrl, 0xf, 0xf, false);          \
    v += _t;                                                                      \
  } while (0)

__device__ __forceinline__ int wave_sum_i32(int v) {
  DPP_STAGE_ADDI(v, 0x111);
  DPP_STAGE_ADDI(v, 0x112);
  DPP_STAGE_ADDI(v, 0x114);
  DPP_STAGE_ADDI(v, 0x118);
  DPP_STAGE_ADDI(v, 0x142);
  DPP_STAGE_ADDI(v, 0x143);
  return __builtin_amdgcn_readlane(v, 63);
}

// ---------------------------------------------------------------- FPS
// One block per batch. 256 threads x 16 CONTIGUOUS points (thread t owns
// [16t,16t+16) -> tie-index lane-monotonic -> ballot+ffs replaces the 6-stage
// DPP min-index chain). MEASURED: 256-thread shape = 644us best; 512-thread =
// 878us (wave-overhead duplication); LDS spin-wait instead of s_barrier =
// 1024us (spin polls are serial LDS latency; barrier is cheap -> REVERTED to
// __syncthreads). Serial 1024 steps, ONE barrier per step. Tie rule: lowest
// index (jnp.argmax). Distances: exact (contract-off) (dx^2+dy^2)+dz^2.
__global__ __launch_bounds__(256) void fps_kernel(const float* __restrict__ xyz,
                                                  float* __restrict__ newxyz) {
#pragma clang fp contract(off)
  const int b = blockIdx.x, t = threadIdx.x;
  __shared__ __align__(16) float s4[NPT * 4];  // xyz padded to 4
  __shared__ unsigned long long s_red[2][4];
  const float* gx = xyz + b * NPT * 3;
  for (int i = t; i < NPT * 3; i += 256) s4[(i / 3) * 4 + (i % 3)] = gx[i];
  __syncthreads();
  v2f px[8], py[8], pz[8], dst[8];
#pragma unroll
  for (int k = 0; k < 8; ++k) {  // contiguous: points 16t+2k, 16t+2k+1
    float4 a = *(const float4*)&s4[(t * 16 + 2 * k) * 4];
    float4 c = *(const float4*)&s4[(t * 16 + 2 * k + 1) * 4];
    px[k].x = a.x; px[k].y = c.x;
    py[k].x = a.y; py[k].y = c.y;
    pz[k].x = a.z; pz[k].y = c.z;
    dst[k].x = 1e10f; dst[k].y = 1e10f;
  }
  float cx = s4[0], cy = s4[1], cz = s4[2];  // start = index 0
  const int w = t >> 6;
  int buf = 0;
  for (int it = 0; it < SP; ++it) {
    if (t == 0) {
      float* o = newxyz + (b * SP + it) * 3;
      o[0] = cx; o[1] = cy; o[2] = cz;
    }
    v2f vcx = splat2(cx), vcy = splat2(cy), vcz = splat2(cz);
    float bd = -1.0f; int bi = 0;
#pragma unroll
    for (int k = 0; k < 8; ++k) {
      v2f dx = px[k] - vcx;
      v2f dy = py[k] - vcy;
      v2f dz = pz[k] - vcz;
      v2f dd = (dx * dx + dy * dy) + dz * dz;  // per-component, no fma
      float n0 = fminf(dst[k].x, dd.x);
      float n1 = fminf(dst[k].y, dd.y);
      dst[k].x = n0; dst[k].y = n1;
      if (n0 > bd) { bd = n0; bi = t * 16 + 2 * k; }      // ascending idx scan:
      if (n1 > bd) { bd = n1; bi = t * 16 + 2 * k + 1; }  // strict > keeps lowest
    }
    float dw = wave_max_f32(bd);
    unsigned long long mask = __ballot(bd == dw);
    int wl = __ffsll(mask) - 1;                                 // lowest candidate lane
    unsigned iw = (unsigned)__builtin_amdgcn_readlane(bi, wl);  // lane-monotonic -> lowest idx
    if ((t & 63) == 0)
      s_red[buf][w] = ((unsigned long long)__float_as_uint(dw) << 32) | (4095u - iw);
    __syncthreads();
    unsigned long long k0 = s_red[buf][0], k1 = s_red[buf][1];
    unsigned long long k2 = s_red[buf][2], k3 = s_red[buf][3];
    unsigned long long ka = k0 > k1 ? k0 : k1;
    unsigned long long kb = k2 > k3 ? k2 : k3;
    unsigned long long km = ka > kb ? ka : kb;
    int p = 4095 - (int)(km & 0xFFFFFFFFull);
    float4 cc = *(const float4*)&s4[p * 4];
    cx = cc.x; cy = cc.y; cz = cc.z;
    buf ^= 1;
  }
}

// ---------------------------------------------------------------- kNN
// One wave per query (4 waves/block). 64 distances/lane in registers.
// Radix binary search on float bits for the exact 32nd-smallest value
// (DPP sum for the wave count), then collect (<T) plus index-ordered (==T)
// fills. Order within the 32 is irrelevant downstream (permutation-invariant).
__global__ __launch_bounds__(256) void knn_kernel(const float* __restrict__ xyz,
                                                  const float* __restrict__ newxyz,
                                                  int* __restrict__ gidx) {
  const int t = threadIdx.x, lane = t & 63, w = t >> 6;
  const int q = blockIdx.x * 4 + w;  // 0..16383
  const int b = q >> 10;
  const float* nx = newxyz + q * 3;
  const float qx = nx[0], qy = nx[1], qz = nx[2];
  const float* xb = xyz + b * NPT * 3;
  float d[64];
#pragma unroll
  for (int j = 0; j < 64; ++j) {
    int p = j * 64 + lane;
    d[j] = sqdist3(xb[p * 3], xb[p * 3 + 1], xb[p * 3 + 2], qx, qy, qz);
  }
  unsigned V = 0;  // becomes bit pattern of the 32nd smallest distance
  for (int bit = 30; bit >= 0; --bit) {
    unsigned cand = V | (1u << bit);
    int c = 0;
#pragma unroll
    for (int j = 0; j < 64; ++j) c += (__float_as_uint(d[j]) < cand) ? 1 : 0;
    int ct = wave_sum_i32(c);
    if (ct < KNB) V = cand;
  }
  __shared__ int s_cnt[4], s_eqcnt[4], s_eq[4][64];
  if (lane == 0) { s_cnt[w] = 0; s_eqcnt[w] = 0; }
  __syncthreads();
  int* gout = gidx + q * KNB;
#pragma unroll
  for (int j = 0; j < 64; ++j) {
    unsigned db = __float_as_uint(d[j]);
    if (db < V) {
      int pos = atomicAdd(&s_cnt[w], 1);
      if (pos < KNB) gout[pos] = j * 64 + lane;
    } else if (db == V) {
      int pos = atomicAdd(&s_eqcnt[w], 1);
      if (pos < 64) s_eq[w][pos] = j * 64 + lane;
    }
  }
  __syncthreads();
  if (lane == 0) {  // fill remaining slots with smallest-index ties
    int c1 = s_cnt[w]; if (c1 > KNB) c1 = KNB;
    int ne = s_eqcnt[w]; if (ne > 64) ne = 64;
    int need = KNB - c1;
    for (int m = 0; m < need; ++m) {
      int bi = -1, bv = 0x7fffffff;
      for (int e = 0; e < ne; ++e) {
        int v = s_eq[w][e];
        if (v < bv) { bv = v; bi = e; }
      }
      gout[c1 + m] = bv;
      if (bi >= 0) s_eq[w][bi] = 0x7fffffff;
    }
  }
}

// ---------------------------------------------------------------- layer 1 (gather + 67->64 + stats)
// 128 rows x 64 outs per block; 4 rows x 8 outs per thread. Inner loop packs
// row-pairs into v2f -> v_pk_fma_f32 (16 packed FMA per c instead of 32 scalar).
// Stats partials written COALESCED as part[blk][2][64].
__global__ __launch_bounds__(256) void layer1_kernel(
    const float* __restrict__ xyz, const float* __restrict__ points,
    const float* __restrict__ newxyz, const int* __restrict__ gidx,
    const float* __restrict__ w1, const float* __restrict__ b1,
    float* __restrict__ h1, float* __restrict__ part) {
  const int t = threadIdx.x, blk = blockIdx.x;
  const int R0 = blk * 128;
  const int b = R0 >> 15;
  __shared__ __align__(16) float xs[67][132];
  __shared__ __align__(16) float wsm[67][68];
  __shared__ float red[2][32][65];
  {
    int o = t & 63;
    for (int c = t >> 6; c < 67; c += 4) wsm[c][o] = w1[o * 67 + c];
  }
  {
    int r = t >> 1, q = t & 1;
    int R = R0 + r;
    int idx = gidx[R];
    if (q == 0) {
      const float* xp = xyz + (size_t)(b * NPT + idx) * 3;
      const float* nq = newxyz + (size_t)(R >> 5) * 3;  // R>>5 == b*1024+s
      xs[0][r] = xp[0] - nq[0];
      xs[1][r] = xp[1] - nq[1];
      xs[2][r] = xp[2] - nq[2];
    }
    const float* pp = points + (size_t)(b * NPT + idx) * CINP + q * 32;
#pragma unroll
    for (int i = 0; i < 8; ++i) {
      float4 v = *(const float4*)(pp + i * 4);
      int c = 3 + q * 32 + i * 4;
      xs[c][r] = v.x; xs[c + 1][r] = v.y; xs[c + 2][r] = v.z; xs[c + 3][r] = v.w;
    }
  }
  __syncthreads();
  const int tr = t & 31, to = t >> 5;  // 4 rows x 8 outs
  v2f acc[2][8];  // [row-pair][out]; pair i2 covers rows {2*i2, 2*i2+1}
#pragma unroll
  for (int j = 0; j < 8; ++j) {
    v2f bb = splat2(b1[to * 8 + j]);
    acc[0][j] = bb; acc[1][j] = bb;
  }
  for (int c = 0; c < 67; ++c) {
    const v2f* xp2 = (const v2f*)&xs[c][tr * 4];  // aligned 16B -> two v2f
    v2f x01 = xp2[0], x23 = xp2[1];
    float4 w0 = *(const float4*)&wsm[c][to * 8];
    float4 w1v = *(const float4*)&wsm[c][to * 8 + 4];
    float wa[8] = {w0.x, w0.y, w0.z, w0.w, w1v.x, w1v.y, w1v.z, w1v.w};
#pragma unroll
    for (int j = 0; j < 8; ++j) {
      v2f ws = splat2(wa[j]);
      acc[0][j] += x01 * ws;  // v_pk_fma_f32
      acc[1][j] += x23 * ws;
    }
  }
#pragma unroll
  for (int i2 = 0; i2 < 2; ++i2)
#pragma unroll
    for (int half = 0; half < 2; ++half) {
      int row = i2 * 2 + half;
      float4 s0, s1;
      s0.x = half ? acc[i2][0].y : acc[i2][0].x;
      s0.y = half ? acc[i2][1].y : acc[i2][1].x;
      s0.z = half ? acc[i2][2].y : acc[i2][2].x;
      s0.w = half ? acc[i2][3].y : acc[i2][3].x;
      s1.x = half ? acc[i2][4].y : acc[i2][4].x;
      s1.y = half ? acc[i2][5].y : acc[i2][5].x;
      s1.z = half ? acc[i2][6].y : acc[i2][6].x;
      s1.w = half ? acc[i2][7].y : acc[i2][7].x;
      float* hp = &h1[(size_t)(R0 + tr * 4 + row) * 64 + to * 8];
      *(float4*)hp = s0;
      *(float4*)(hp + 4) = s1;
    }
#pragma unroll
  for (int j = 0; j < 8; ++j) {
    v2f p01 = acc[0][j], p23 = acc[1][j];
    float s1 = (p01.x + p01.y) + (p23.x + p23.y);
    float s2 = (p01.x * p01.x + p01.y * p01.y) + (p23.x * p23.x + p23.y * p23.y);
    red[0][tr][to * 8 + j] = s1;
    red[1][tr][to * 8 + j] = s2;
  }
  __syncthreads();
  if (t < 128) {
    int stat = t >> 6, o = t & 63;
    float v = 0.f;
#pragma unroll
    for (int k = 0; k < 32; ++k) v += red[stat][k][o];
    part[(size_t)blk * 128 + t] = v;  // coalesced [blk][2][64]
  }
}

// ---------------------------------------------------------------- layer 2 (bn1+relu fold, 64->64 + stats)
// 128 rows x 64 outs; IN-PLACE (hin/hout alias -> NOT restrict; stage to LDS
// first; blocks own disjoint rows). v_pk_fma inner loop; coalesced stats.
__global__ __launch_bounds__(256) void layer2_kernel(
    const float* hin, const float* __restrict__ bn,
    const float* __restrict__ w2, const float* __restrict__ b2,
    float* hout, float* __restrict__ part) {
  const int t = threadIdx.x, blk = blockIdx.x;
  const size_t R0 = (size_t)blk * 128;
  __shared__ __align__(16) float xs[64][132];
  __shared__ __align__(16) float wsm[64][68];
  __shared__ float red[2][32][65];
  {
    int o = t & 63;
    for (int c = t >> 6; c < 64; c += 4) wsm[c][o] = w2[o * 64 + c];
  }
  {
    int r = t >> 1, q = t & 1;
    const float* hp = hin + (R0 + r) * 64 + q * 32;
#pragma unroll
    for (int i = 0; i < 8; ++i) {
      int c = q * 32 + i * 4;
      float4 v = *(const float4*)(hp + i * 4);
      float4 sc = *(const float4*)(bn + c);
      float4 sh = *(const float4*)(bn + 64 + c);
      xs[c][r]     = fmaxf(v.x * sc.x + sh.x, 0.f);
      xs[c + 1][r] = fmaxf(v.y * sc.y + sh.y, 0.f);
      xs[c + 2][r] = fmaxf(v.z * sc.z + sh.z, 0.f);
      xs[c + 3][r] = fmaxf(v.w * sc.w + sh.w, 0.f);
    }
  }
  __syncthreads();
  const int tr = t & 31, to = t >> 5;
  v2f acc[2][8];
#pragma unroll
  for (int j = 0; j < 8; ++j) {
    v2f bb = splat2(b2[to * 8 + j]);
    acc[0][j] = bb; acc[1][j] = bb;
  }
  for (int c = 0; c < 64; ++c) {
    const v2f* xp2 = (const v2f*)&xs[c][tr * 4];
    v2f x01 = xp2[0], x23 = xp2[1];
    float4 w0 = *(const float4*)&wsm[c][to * 8];
    float4 w1v = *(const float4*)&wsm[c][to * 8 + 4];
    float wa[8] = {w0.x, w0.y, w0.z, w0.w, w1v.x, w1v.y, w1v.z, w1v.w};
#pragma unroll
    for (int j = 0; j < 8; ++j) {
      v2f ws = splat2(wa[j]);
      acc[0][j] += x01 * ws;
      acc[1][j] += x23 * ws;
    }
  }
#pragma unroll
  for (int i2 = 0; i2 < 2; ++i2)
#pragma unroll
    for (int half = 0; half < 2; ++half) {
      int row = i2 * 2 + half;
      float4 s0, s1;
      s0.x = half ? acc[i2][0].y : acc[i2][0].x;
      s0.y = half ? acc[i2][1].y : acc[i2][1].x;
      s0.z = half ? acc[i2][2].y : acc[i2][2].x;
      s0.w = half ? acc[i2][3].y : acc[i2][3].x;
      s1.x = half ? acc[i2][4].y : acc[i2][4].x;
      s1.y = half ? acc[i2][5].y : acc[i2][5].x;
      s1.z = half ? acc[i2][6].y : acc[i2][6].x;
      s1.w = half ? acc[i2][7].y : acc[i2][7].x;
      float* hp = &hout[(R0 + tr * 4 + row) * 64 + to * 8];
      *(float4*)hp = s0;
      *(float4*)(hp + 4) = s1;
    }
#pragma unroll
  for (int j = 0; j < 8; ++j) {
    v2f p01 = acc[0][j], p23 = acc[1][j];
    float s1 = (p01.x + p01.y) + (p23.x + p23.y);
    float s2 = (p01.x * p01.x + p01.y * p01.y) + (p23.x * p23.x + p23.y * p23.y);
    red[0][tr][to * 8 + j] = s1;
    red[1][tr][to * 8 + j] = s2;
  }
  __syncthreads();
  if (t < 128) {
    int stat = t >> 6, o = t & 63;
    float v = 0.f;
#pragma unroll
    for (int k = 0; k < 32; ++k) v += red[stat][k][o];
    part[(size_t)blk * 128 + t] = v;  // coalesced [blk][2][64]
  }
}

// ---------------------------------------------------------------- layer 3 (bn2+relu fold, 64->128, stats + max/min pool over k)
// v_pk_fma inner loop; red overlay stride 129; coalesced stats part[blk][2][128].
__global__ __launch_bounds__(256) void layer3_kernel(
    const float* __restrict__ hin, const float* __restrict__ bn,
    const float* __restrict__ w3, const float* __restrict__ b3,
    float* __restrict__ maxh, float* __restrict__ minh, float* __restrict__ part) {
  const int t = threadIdx.x, blk = blockIdx.x;
  const size_t R0 = (size_t)blk * 64;
  __shared__ __align__(16) float smem[64 * 68 + 64 * 136];  // xs | wsm (red overlays xs later)
  float* xs = smem;            // [64][68]
  float* wsm = smem + 64 * 68; // [64][136]
  {
    int o = t & 127, q = t >> 7;
    for (int c = q; c < 64; c += 2) wsm[c * 136 + o] = w3[o * 64 + c];
  }
  {
    int r = t >> 2, q = t & 3;
    const float* hp = hin + (R0 + r) * 64 + q * 16;
#pragma unroll
    for (int i = 0; i < 4; ++i) {
      int c = q * 16 + i * 4;
      float4 v = *(const float4*)(hp + i * 4);
      float4 sc = *(const float4*)(bn + c);
      float4 sh = *(const float4*)(bn + 64 + c);
      xs[c * 68 + r]       = fmaxf(v.x * sc.x + sh.x, 0.f);
      xs[(c + 1) * 68 + r] = fmaxf(v.y * sc.y + sh.y, 0.f);
      xs[(c + 2) * 68 + r] = fmaxf(v.z * sc.z + sh.z, 0.f);
      xs[(c + 3) * 68 + r] = fmaxf(v.w * sc.w + sh.w, 0.f);
    }
  }
  __syncthreads();
  const int tr = t & 15, to = t >> 4;  // 4 rows x 8 outs per thread
  v2f acc[2][8];
#pragma unroll
  for (int j = 0; j < 8; ++j) {
    v2f bb = splat2(b3[to * 8 + j]);
    acc[0][j] = bb; acc[1][j] = bb;
  }
  for (int c = 0; c < 64; ++c) {
    const v2f* xp2 = (const v2f*)&xs[c * 68 + tr * 4];
    v2f x01 = xp2[0], x23 = xp2[1];
    float4 wv0 = *(const float4*)&wsm[c * 136 + to * 8];
    float4 wv1 = *(const float4*)&wsm[c * 136 + to * 8 + 4];
    float wa[8] = {wv0.x, wv0.y, wv0.z, wv0.w, wv1.x, wv1.y, wv1.z, wv1.w};
#pragma unroll
    for (int j = 0; j < 8; ++j) {
      v2f ws = splat2(wa[j]);
      acc[0][j] += x01 * ws;
      acc[1][j] += x23 * ws;
    }
  }
  __syncthreads();  // xs reads done; reuse as reduction buffer
  float* red = smem;  // [2][16][129] = 4128 floats <= 4352
#pragma unroll
  for (int j = 0; j < 8; ++j) {
    v2f p01 = acc[0][j], p23 = acc[1][j];
    float s1 = (p01.x + p01.y) + (p23.x + p23.y);
    float s2 = (p01.x * p01.x + p01.y * p01.y) + (p23.x * p23.x + p23.y * p23.y);
    red[(0 * 16 + tr) * 129 + to * 8 + j] = s1;
    red[(1 * 16 + tr) * 129 + to * 8 + j] = s2;
  }
  __syncthreads();
  {
    int stat = t >> 7, o = t & 127;
    float v = 0.f;
#pragma unroll
    for (int k = 0; k < 16; ++k) v += red[(stat * 16 + k) * 129 + o];
    part[(size_t)blk * 256 + t] = v;  // coalesced [blk][2][128]
  }
  __syncthreads();
#pragma unroll
  for (int j = 0; j < 8; ++j) {
    v2f p01 = acc[0][j], p23 = acc[1][j];
    float mx = fmaxf(fmaxf(p01.x, p01.y), fmaxf(p23.x, p23.y));
    float mn = fminf(fminf(p01.x, p01.y), fminf(p23.x, p23.y));
    red[(0 * 16 + tr) * 129 + to * 8 + j] = mx;
    red[(1 * 16 + tr) * 129 + to * 8 + j] = mn;
  }
  __syncthreads();
  {
    int g = t >> 7, o = t & 127;  // 2 s-rows per block (k=32 inner)
    float mx = -1e30f, mn = 1e30f;
#pragma unroll
    for (int k = 0; k < 8; ++k) {
      mx = fmaxf(mx, red[(0 * 16 + g * 8 + k) * 129 + o]);
      mn = fminf(mn, red[(1 * 16 + g * 8 + k) * 129 + o]);
    }
    size_t bs = (size_t)blk * 2 + g;
    maxh[bs * 128 + o] = mx;
    minh[bs * 128 + o] = mn;
  }
}

// ---------------------------------------------------------------- BN reduce: part[nblk][2][Cout] column-sum -> scale/shift (1 dispatch/layer)
__global__ __launch_bounds__(256) void bn_reduce(const float* __restrict__ part,
                                                 const float* __restrict__ g,
                                                 const float* __restrict__ be,
                                                 float* __restrict__ bnout,
                                                 int Cout, int nblk) {
  const int o = blockIdx.x, t = threadIdx.x;
  const int row = 2 * Cout;
  float s1 = 0.f, s2 = 0.f;
  for (int r = t; r < nblk; r += 256) {
    const float* p = part + (size_t)r * row;
    s1 += p[o];
    s2 += p[Cout + o];
  }
#pragma unroll
  for (int off = 32; off >= 1; off >>= 1) {
    s1 += __shfl_xor(s1, off);
    s2 += __shfl_xor(s2, off);
  }
  __shared__ float r1[4], r2[4];
  if ((t & 63) == 0) { r1[t >> 6] = s1; r2[t >> 6] = s2; }
  __syncthreads();
  if (t == 0) {
    float S1 = r1[0] + r1[1] + r1[2] + r1[3];
    float S2 = r2[0] + r2[1] + r2[2] + r2[3];
    float m = S1 / NT_F;
    float v = S2 / NT_F - m * m;
    if (v < 0.f) v = 0.f;
    float inv = 1.0f / sqrtf(v + 1e-5f);
    float sc = g[o] * inv;
    bnout[o] = sc;
    bnout[Cout + o] = be[o] - m * sc;
  }
}

// ---------------------------------------------------------------- final: out = max(relu(sc*maxh+sh), relu(sc*minh+sh))
// (exact for max_k relu(sc*h+sh) for any sign of sc)
__global__ __launch_bounds__(256) void finalize_kernel(const float* __restrict__ maxh,
                                                       const float* __restrict__ minh,
                                                       const float* __restrict__ bn,
                                                       float* __restrict__ out2) {
  int i = blockIdx.x * 256 + threadIdx.x;  // 2,097,152 total
  int o = i & 127;
  float sc = bn[o], sh = bn[128 + o];
  float a = sc * maxh[i] + sh;
  float c = sc * minh[i] + sh;
  out2[i] = fmaxf(fmaxf(a, c), 0.f);
}

extern "C" void kernel_launch(void* const* d_in, const int* in_sizes, int n_in,
                              void* d_out, int out_size, void* d_ws, size_t ws_size,
                              hipStream_t stream) {
  const float* xyz = (const float*)d_in[0];
  const float* points = (const float*)d_in[1];
  const float* w1 = (const float*)d_in[2];
  const float* b1 = (const float*)d_in[3];
  const float* g1 = (const float*)d_in[4];
  const float* be1 = (const float*)d_in[5];
  const float* w2 = (const float*)d_in[6];
  const float* b2 = (const float*)d_in[7];
  const float* g2 = (const float*)d_in[8];
  const float* be2 = (const float*)d_in[9];
  const float* w3 = (const float*)d_in[10];
  const float* b3 = (const float*)d_in[11];
  const float* g3 = (const float*)d_in[12];
  const float* be3 = (const float*)d_in[13];

  float* out = (float*)d_out;
  float* newxyz = out;           // [16,1024,3]
  float* out2 = out + 49152;     // [16,1024,128]

  // workspace layout (~154 MiB):
  // [gidx 2MiB (bn buffers @1MiB)][h 128MiB (layer2 in-place)][part 8MiB][maxh 8MiB][minh 8MiB]
  const size_t MiB = 1u << 20;
  char* wsb = (char*)d_ws;
  int*   gidx = (int*)wsb;
  float* bn1  = (float*)(wsb + 1 * MiB);
  float* bn2  = bn1 + 256;
  float* bn3  = bn2 + 256;
  float* h    = (float*)(wsb + 2 * MiB);
  float* part = (float*)(wsb + 130 * MiB);
  float* maxh = (float*)(wsb + 138 * MiB);
  float* minh = (float*)(wsb + 146 * MiB);

  hipLaunchKernelGGL(fps_kernel, dim3(NB), dim3(256), 0, stream, xyz, newxyz);
  hipLaunchKernelGGL(knn_kernel, dim3(16384 / 4), dim3(256), 0, stream, xyz, newxyz, gidx);
  hipLaunchKernelGGL(layer1_kernel, dim3(NBLK12), dim3(256), 0, stream,
                     xyz, points, newxyz, gidx, w1, b1, h, part);
  hipLaunchKernelGGL(bn_reduce, dim3(64), dim3(256), 0, stream, part, g1, be1, bn1, 64, NBLK12);
  hipLaunchKernelGGL(layer2_kernel, dim3(NBLK12), dim3(256), 0, stream, h, bn1, w2, b2, h, part);
  hipLaunchKernelGGL(bn_reduce, dim3(64), dim3(256), 0, stream, part, g2, be2, bn2, 64, NBLK12);
  hipLaunchKernelGGL(layer3_kernel, dim3(NBLK3), dim3(256), 0, stream,
                     h, bn2, w3, b3, maxh, minh, part);
  hipLaunchKernelGGL(bn_reduce, dim3(128), dim3(256), 0, stream, part, g3, be3, bn3, 128, NBLK3);
  hipLaunchKernelGGL(finalize_kernel, dim3(2097152 / 256), dim3(256), 0, stream,
                     maxh, minh, bn3, out2);
}